// Round 1
// 1042.900 us; speedup vs baseline: 1.0372x; 1.0372x over previous
//
#include <hip/hip_runtime.h>
#include <hip/hip_bf16.h>
#include <stdint.h>

typedef unsigned short u16;
typedef __attribute__((ext_vector_type(8))) short bf16x8;
typedef __attribute__((ext_vector_type(4))) float f32x4;

constexpr int T_ = 8192;
constexpr int D_ = 1024;
constexpr int H_ = 4096;
constexpr int E_ = 8;
constexpr int MAXROWS = 25600;   // 200 tiles * 128 rows (worst-case padded)
constexpr int NTILES  = 200;

__device__ __forceinline__ unsigned int f2bf_bits(float f) {
  unsigned int u = __float_as_uint(f);
  return (u + 0x7fffu + ((u >> 16) & 1u)) >> 16;
}

__device__ __forceinline__ void load_lds16(const void* g, void* s) {
  __builtin_amdgcn_global_load_lds(
      (const __attribute__((address_space(1))) unsigned int*)g,
      (__attribute__((address_space(3))) unsigned int*)s, 16, 0, 0);
}

// ---------------- router: fp32 logits, top-2, renormalized weights ----------
__global__ __launch_bounds__(256) void router_kernel(
    const float* __restrict__ x, const float* __restrict__ rw,
    int* __restrict__ counts, int* __restrict__ tok2, float* __restrict__ wgt2) {
  __shared__ float rw_s[E_ * D_];   // transposed [e][d] -> conflict-free reads
  __shared__ int c_s[E_];
  const int tid = threadIdx.x;
  if (tid < E_) c_s[tid] = 0;
  for (int f = tid; f < 2048; f += 256) {
    int d = f >> 1, p = f & 1;
    float4 v = *(const float4*)(rw + d * 8 + p * 4);
    rw_s[(p * 4 + 0) * D_ + d] = v.x;
    rw_s[(p * 4 + 1) * D_ + d] = v.y;
    rw_s[(p * 4 + 2) * D_ + d] = v.z;
    rw_s[(p * 4 + 3) * D_ + d] = v.w;
  }
  __syncthreads();
  const int wid = tid >> 6, lane = tid & 63;
  for (int ti = 0; ti < 16; ++ti) {
    const int t = blockIdx.x * 64 + wid * 16 + ti;
    const float* xr = x + (long)t * D_;
    float acc[E_] = {0.f, 0.f, 0.f, 0.f, 0.f, 0.f, 0.f, 0.f};
    for (int j = 0; j < 16; ++j) {
      const int d = lane + 64 * j;
      const float xv = xr[d];
#pragma unroll
      for (int e = 0; e < E_; ++e) acc[e] += xv * rw_s[e * D_ + d];
    }
#pragma unroll
    for (int off = 32; off >= 1; off >>= 1) {
#pragma unroll
      for (int e = 0; e < E_; ++e) acc[e] += __shfl_xor(acc[e], off, 64);
    }
    if (lane == 0) {
      int i0 = 0; float l0 = acc[0];
#pragma unroll
      for (int e = 1; e < E_; ++e) if (acc[e] > l0) { l0 = acc[e]; i0 = e; }
      int i1 = -1; float l1 = -3.4e38f;
#pragma unroll
      for (int e = 0; e < E_; ++e) if (e != i0 && acc[e] > l1) { l1 = acc[e]; i1 = e; }
      // renormalized top-2 weights: softmax denom cancels
      const float r = __expf(l1 - l0);
      const float inv = 1.f / (1.f + r);
      tok2[2 * t] = i0; tok2[2 * t + 1] = i1;
      wgt2[2 * t] = inv; wgt2[2 * t + 1] = r * inv;
      atomicAdd(&c_s[i0], 1); atomicAdd(&c_s[i1], 1);
    }
  }
  __syncthreads();
  if (tid < E_) atomicAdd(&counts[tid], c_s[tid]);
}

// ---------------- scan: 128-aligned offsets, tile->expert table ------------
__global__ void scan_kernel(const int* __restrict__ counts, int* __restrict__ offs,
                            int* __restrict__ tile_expert, int* __restrict__ rowtok) {
  __shared__ int so[10];
  const int tid = threadIdx.x;
  if (tid == 0) {
    int o = 0;
    for (int e = 0; e < E_; ++e) { so[e] = o; o += ((counts[e] + 127) >> 7) << 7; }
    so[8] = o;          // shared-expert row base
    o += T_;
    so[9] = o;          // actual total rows (<= MAXROWS)
    for (int i = 0; i < 10; ++i) offs[i] = so[i];
  }
  __syncthreads();
  for (int i = tid; i < NTILES; i += 256) {
    const int row = i << 7;
    int e = 8;
    if (row < so[8]) {
      e = 7;
      for (int k = 0; k < 7; ++k) if (row < so[k + 1]) { e = k; break; }
    }
    tile_expert[i] = e;
  }
  // default token 0 everywhere; assign_kernel overwrites the live entries
  for (int r = tid; r < MAXROWS; r += 256) rowtok[r] = 0;
}

// ---------------- assign: scatter tokens into per-expert row ranges --------
__global__ __launch_bounds__(256) void assign_kernel(
    const int* __restrict__ tok2, const int* __restrict__ offs,
    int* __restrict__ cursors, int* __restrict__ rowtok, int* __restrict__ pos2) {
  __shared__ int lcnt[E_], lbase[E_];
  const int tid = threadIdx.x;
  if (tid < E_) lcnt[tid] = 0;
  __syncthreads();
  const int t = blockIdx.x * 256 + tid;
  const int e0 = tok2[2 * t], e1 = tok2[2 * t + 1];
  const int s0 = atomicAdd(&lcnt[e0], 1);
  const int s1 = atomicAdd(&lcnt[e1], 1);
  __syncthreads();
  if (tid < E_) lbase[tid] = offs[tid] + atomicAdd(&cursors[tid], lcnt[tid]);
  __syncthreads();
  const int p0 = lbase[e0] + s0, p1 = lbase[e1] + s1;
  rowtok[p0] = t; rowtok[p1] = t;
  pos2[2 * t] = p0; pos2[2 * t + 1] = p1;
  rowtok[offs[8] + t] = t;   // shared expert: identity
}

// ---------------- x fp32 -> bf16 -------------------------------------------
__global__ __launch_bounds__(256) void cvt_x_kernel(const float* __restrict__ x,
                                                    u16* __restrict__ xb) {
  const long i = ((long)blockIdx.x * 256 + threadIdx.x) * 4;
  const float4 v = *(const float4*)(x + i);
  ushort4 o;
  o.x = (u16)f2bf_bits(v.x); o.y = (u16)f2bf_bits(v.y);
  o.z = (u16)f2bf_bits(v.z); o.w = (u16)f2bf_bits(v.w);
  *(ushort4*)(xb + i) = o;
}

// ---------------- weight transpose + fp32->bf16 ([R,C] -> [C,R]) -----------
// blockIdx.z in [0,9): z<8 -> routed expert z, z==8 -> shared weight
__global__ __launch_bounds__(256) void transpose_cvt_kernel(
    const float* __restrict__ src8, const float* __restrict__ srcShared,
    u16* __restrict__ dst, int R, int C) {
  __shared__ float tile[64][65];
  const long stride = (long)R * C;
  const float* src = (blockIdx.z < 8) ? src8 + (long)blockIdx.z * stride : srcShared;
  u16* d = dst + (long)blockIdx.z * stride;
  const int tid = threadIdx.x;
  const int r0 = blockIdx.y * 64, c0 = blockIdx.x * 64;
  const int lr = tid >> 4, lc4 = tid & 15;
#pragma unroll
  for (int p = 0; p < 4; ++p) {
    const float4 v = *(const float4*)(src + (long)(r0 + lr + 16 * p) * C + c0 + lc4 * 4);
    tile[lr + 16 * p][lc4 * 4 + 0] = v.x;
    tile[lr + 16 * p][lc4 * 4 + 1] = v.y;
    tile[lr + 16 * p][lc4 * 4 + 2] = v.z;
    tile[lr + 16 * p][lc4 * 4 + 3] = v.w;
  }
  __syncthreads();
#pragma unroll
  for (int p = 0; p < 4; ++p) {
    const int rr = lr + 16 * p;          // index along C (dst row)
    ushort4 o;
    o.x = (u16)f2bf_bits(tile[lc4 * 4 + 0][rr]);
    o.y = (u16)f2bf_bits(tile[lc4 * 4 + 1][rr]);
    o.z = (u16)f2bf_bits(tile[lc4 * 4 + 2][rr]);
    o.w = (u16)f2bf_bits(tile[lc4 * 4 + 3][rr]);
    *(ushort4*)(d + (long)(c0 + rr) * R + r0 + lc4 * 4) = o;
  }
}

// ---------------- grouped GEMM (3-buf ring, counted vmcnt, swizzled LDS) ----
// G1: C[row,n] = silu( sum_k x_bf16[rowtok[row],k] * w1t[e][n,k] )  -> h bf16
// G2: C[row,n] = sum_k h[row,k] * w2t[e][n,k]                       -> eo fp32
//
// Pipeline: 3 LDS buffers (8KB A + 8KB B each), prefetch depth 2 sub-iters.
// Each sub-iter: s_waitcnt vmcnt(4) [waits ONLY the current buffer's 4
// global_load_lds; the next buffer's 4 stay in flight across the barrier,
// T4 counted-vmcnt] -> s_barrier -> issue 4 loads for buf j+2 -> ds_read ->
// 16 MFMA (setprio-wrapped). Load issued at iter j overwrites buf (j-1)%3,
// whose reads all retired before barrier j (lgkmcnt drained pre-MFMA) -> safe.
// The ONLY VMEM ops inside the loop are the 4 staging loads, so vmcnt
// counting is exact (no spills: ~150 unified regs).
//
// Bank conflicts: LDS rows are 64B; linear layout puts 16 stride-64B lane
// reads in 2 of 8 bank-groups (4-way conflict, 2.6e7/dispatch measured).
// Fix: store global chunk (c ^ ((row>>1)&3)) at LDS chunk c by pre-swizzling
// the per-lane GLOBAL source address (global_load_lds dest must stay linear),
// and read at chunk (quad ^ ((lr>>1)&3)). Every contiguous 8-lane phase then
// hits all 8 bank-groups exactly once -> conflict-free b128 reads.
template <bool G1, int CHM>
__global__ __launch_bounds__(256) void moe_gemm(
    const u16* __restrict__ A, const u16* __restrict__ Bt, void* __restrict__ C,
    const int* __restrict__ rowtok, const int* __restrict__ tile_expert) {
  constexpr int K = G1 ? 1024 : 4096;
  constexpr int N = G1 ? 4096 : 1024;
  constexpr int NT = N / 128;
  constexpr int NIT = K / 32;          // sub-iters of 32 k
  __shared__ u16 As[3 * 4096];   // 3 x (128 rows x 32 k) bf16 = 24 KB
  __shared__ u16 Bs[3 * 4096];

  const int tid = threadIdx.x;
  int mt, nt;
  {
    const int bid = blockIdx.x;
    const int cb = CHM * NT;                 // blocks per full chunk
    const int chunk = bid / cb;
    const int mt0 = chunk * CHM;
    const int m = min(CHM, NTILES - mt0);    // last chunk may be short
    const int rem = bid - chunk * cb;
    mt = mt0 + rem % m;
    nt = rem / m;
  }
  const int e = tile_expert[mt];

  const int sr = tid >> 2;                       // staging row 0..63
  // pre-swizzled source chunk: LDS[row][c] <- global[row][c ^ ((row>>1)&3)]
  const int sc = (((tid & 3) ^ ((sr >> 1) & 3)) << 3);

  long aoff0, aoff1;
  if constexpr (G1) {
    aoff0 = (long)rowtok[mt * 128 + sr] * K;
    aoff1 = (long)rowtok[mt * 128 + 64 + sr] * K;
  } else {
    aoff0 = (long)(mt * 128 + sr) * K;
    aoff1 = (long)(mt * 128 + 64 + sr) * K;
  }
  const u16* pa0 = A + aoff0 + sc;
  const u16* pa1 = A + aoff1 + sc;
  const u16* pb0 = Bt + (long)e * N * K + (long)(nt * 128 + sr) * K + sc;
  const u16* pb1 = pb0 + (long)64 * K;

  const int lane = tid & 63;
  const int wid = tid >> 6;
  const int wm = (wid >> 1) * 64;
  const int wn = (wid & 1) * 64;
  const int lr = lane & 15;
  const int quad = lane >> 4;
  // swizzled read chunk (u16 elements): quad ^ ((lr>>1)&3)
  const int cA = ((quad ^ ((lr >> 1) & 3)) << 3);

  f32x4 acc[4][4] = {};

  auto stage = [&](int b, int koff) {
    u16* a_d = As + b * 4096 + tid * 8;   // linear dest (HW: base + lane*16B)
    u16* b_d = Bs + b * 4096 + tid * 8;
    load_lds16(pa0 + koff, a_d);
    load_lds16(pa1 + koff, a_d + 2048);
    load_lds16(pb0 + koff, b_d);
    load_lds16(pb1 + koff, b_d + 2048);
  };
  auto compute = [&](int b) {
    const u16* a_s = As + b * 4096;
    const u16* b_s = Bs + b * 4096;
    bf16x8 af[4], bfv[4];
#pragma unroll
    for (int i = 0; i < 4; ++i)
      af[i] = *(const bf16x8*)(a_s + (wm + i * 16 + lr) * 32 + cA);
#pragma unroll
    for (int j2 = 0; j2 < 4; ++j2)
      bfv[j2] = *(const bf16x8*)(b_s + (wn + j2 * 16 + lr) * 32 + cA);
    __builtin_amdgcn_s_setprio(1);
#pragma unroll
    for (int i = 0; i < 4; ++i)
#pragma unroll
      for (int j2 = 0; j2 < 4; ++j2)
        acc[i][j2] =
            __builtin_amdgcn_mfma_f32_16x16x32_bf16(af[i], bfv[j2], acc[i][j2], 0, 0, 0);
    __builtin_amdgcn_s_setprio(0);
  };

  // prologue: 2-deep prefetch. The empty memory-clobber asm keeps buf0's 4
  // loads strictly older than buf1's in issue order (vmcnt counts by age).
  stage(0, 0);
  asm volatile("" ::: "memory");
  stage(1, 32);

  int cur = 0;
#pragma unroll 1
  for (int j = 0; j < NIT - 1; ++j) {
    // wait current buffer's loads (oldest 4 of 8 outstanding), then sync.
    asm volatile("s_waitcnt vmcnt(4)\n\ts_barrier" ::: "memory");
    if (j + 2 < NIT) {
      const int nb = (cur == 0) ? 2 : cur - 1;   // (j+2)%3 == (j-1)%3: safe,
      stage(nb, (j + 2) * 32);                   // its reads retired pre-barrier
    }
    compute(cur);
    cur = (cur == 2) ? 0 : cur + 1;
  }
  // peeled last sub-iter: only its own 4 loads remain outstanding.
  asm volatile("s_waitcnt vmcnt(0)\n\ts_barrier" ::: "memory");
  compute(cur);

  const int rbase = mt * 128 + wm + quad * 4;
  if constexpr (G1) {
    u16* Hout = (u16*)C;
#pragma unroll
    for (int i = 0; i < 4; ++i) {
#pragma unroll
      for (int j = 0; j < 4; ++j) {
#pragma unroll
        for (int r = 0; r < 4; ++r) {
          float v = acc[i][j][r];
          v = v / (1.f + __expf(-v));            // silu
          unsigned int u = f2bf_bits(v);
          unsigned int other = (unsigned int)__shfl_xor((int)u, 1, 64);
          if (!(lane & 1)) {                      // pack col pairs -> dword store
            const unsigned int w = (u & 0xffffu) | (other << 16);
            const long row = rbase + i * 16 + r;
            const int col = nt * 128 + wn + j * 16 + lr;
            *(unsigned int*)(Hout + row * N + col) = w;
          }
        }
      }
    }
  } else {
    float* O = (float*)C;
#pragma unroll
    for (int i = 0; i < 4; ++i)
#pragma unroll
      for (int j = 0; j < 4; ++j)
#pragma unroll
        for (int r = 0; r < 4; ++r) {
          const long row = rbase + i * 16 + r;
          const int col = nt * 128 + wn + j * 16 + lr;
          O[row * N + col] = acc[i][j][r];
        }
  }
}

// ---------------- combine: out = w0*eo[p0] + w1*eo[p1] + eo[shared] ---------
__global__ __launch_bounds__(256) void combine_kernel(
    const float* __restrict__ eo, const int* __restrict__ pos2,
    const float* __restrict__ wgt2, const int* __restrict__ offs,
    float* __restrict__ out) {
  const int t = blockIdx.x, tid = threadIdx.x;
  const int p0 = pos2[2 * t], p1 = pos2[2 * t + 1];
  const float w0 = wgt2[2 * t], w1 = wgt2[2 * t + 1];
  const int ps = offs[8] + t;
  const long c = (long)tid * 4;
  const float4 a = *(const float4*)(eo + (long)p0 * D_ + c);
  const float4 b = *(const float4*)(eo + (long)p1 * D_ + c);
  const float4 s = *(const float4*)(eo + (long)ps * D_ + c);
  float4 o;
  o.x = w0 * a.x + w1 * b.x + s.x;
  o.y = w0 * a.y + w1 * b.y + s.y;
  o.z = w0 * a.z + w1 * b.z + s.z;
  o.w = w0 * a.w + w1 * b.w + s.w;
  *(float4*)(out + (long)t * D_ + c) = o;
}

// ---------------------------------------------------------------------------
extern "C" void kernel_launch(void* const* d_in, const int* in_sizes, int n_in,
                              void* d_out, int out_size, void* d_ws, size_t ws_size,
                              hipStream_t stream) {
  const float* x   = (const float*)d_in[0];   // [T, D]
  const float* rw  = (const float*)d_in[1];   // [D, E]
  const float* w1  = (const float*)d_in[2];   // [E, D, H]
  const float* w2  = (const float*)d_in[3];   // [E, H, D]
  const float* sw1 = (const float*)d_in[4];   // [D, H]
  const float* sw2 = (const float*)d_in[5];   // [H, D]
  float* out = (float*)d_out;

  char* ws = (char*)d_ws;
  int*   counts      = (int*)(ws + 0);
  int*   cursors     = (int*)(ws + 64);
  int*   offs        = (int*)(ws + 128);
  int*   tile_expert = (int*)(ws + 192);
  int*   tok2        = (int*)(ws + 4096);
  float* wgt2        = (float*)(ws + 4096 + 65536);
  int*   pos2        = (int*)(ws + 4096 + 131072);
  int*   rowtok      = (int*)(ws + 4096 + 196608);

  size_t off = 1u << 20;
  u16* xb  = (u16*)(ws + off); off += (size_t)T_ * D_ * 2;            // 16.8 MB
  u16* w1t = (u16*)(ws + off); off += (size_t)9 * H_ * D_ * 2;        // 75.5 MB
  u16* w2t = (u16*)(ws + off); off += (size_t)9 * D_ * H_ * 2;        // 75.5 MB
  u16* h   = (u16*)(ws + off); off += (size_t)MAXROWS * H_ * 2;       // 209.7 MB
  float* eo = (float*)(ws + off); off += (size_t)MAXROWS * D_ * 4;    // 104.9 MB

  hipMemsetAsync(ws, 0, 256, stream);   // counts + cursors
  router_kernel<<<128, 256, 0, stream>>>(x, rw, counts, tok2, wgt2);
  scan_kernel<<<1, 256, 0, stream>>>(counts, offs, tile_expert, rowtok);
  assign_kernel<<<32, 256, 0, stream>>>(tok2, offs, cursors, rowtok, pos2);
  cvt_x_kernel<<<T_ * D_ / 1024, 256, 0, stream>>>(x, xb);
  transpose_cvt_kernel<<<dim3(H_ / 64, D_ / 64, 9), 256, 0, stream>>>(w1, sw1, w1t, D_, H_);
  transpose_cvt_kernel<<<dim3(D_ / 64, H_ / 64, 9), 256, 0, stream>>>(w2, sw2, w2t, H_, D_);
  // G1: chunk = 24 mt x 32 nt = 768 blocks (~one concurrent fill @3 blk/CU)
  moe_gemm<true, 24><<<NTILES * (H_ / 128), 256, 0, stream>>>(xb, w1t, h, rowtok, tile_expert);
  // G2: chunk = 64 mt x 8 nt = 512 blocks
  moe_gemm<false, 64><<<NTILES * (D_ / 128), 256, 0, stream>>>(h, w2t, eo, rowtok, tile_expert);
  combine_kernel<<<T_, 256, 0, stream>>>(eo, pos2, wgt2, offs, out);
}

// Round 2
// 1023.793 us; speedup vs baseline: 1.0566x; 1.0187x over previous
//
#include <hip/hip_runtime.h>
#include <hip/hip_bf16.h>
#include <stdint.h>

typedef unsigned short u16;
typedef __attribute__((ext_vector_type(8))) short bf16x8;
typedef __attribute__((ext_vector_type(4))) float f32x4;

constexpr int T_ = 8192;
constexpr int D_ = 1024;
constexpr int H_ = 4096;
constexpr int E_ = 8;
constexpr int MAXROWS = 25600;   // 200 tiles * 128 rows (worst-case padded)
constexpr int NTILES  = 200;

__device__ __forceinline__ unsigned int f2bf_bits(float f) {
  unsigned int u = __float_as_uint(f);
  return (u + 0x7fffu + ((u >> 16) & 1u)) >> 16;
}

__device__ __forceinline__ void load_lds16(const void* g, void* s) {
  __builtin_amdgcn_global_load_lds(
      (const __attribute__((address_space(1))) unsigned int*)g,
      (__attribute__((address_space(3))) unsigned int*)s, 16, 0, 0);
}

// ---------------- router: fp32 logits, top-2, renormalized weights ----------
__global__ __launch_bounds__(256) void router_kernel(
    const float* __restrict__ x, const float* __restrict__ rw,
    int* __restrict__ counts, int* __restrict__ tok2, float* __restrict__ wgt2) {
  __shared__ float rw_s[E_ * D_];   // transposed [e][d] -> conflict-free reads
  __shared__ int c_s[E_];
  const int tid = threadIdx.x;
  if (tid < E_) c_s[tid] = 0;
  for (int f = tid; f < 2048; f += 256) {
    int d = f >> 1, p = f & 1;
    float4 v = *(const float4*)(rw + d * 8 + p * 4);
    rw_s[(p * 4 + 0) * D_ + d] = v.x;
    rw_s[(p * 4 + 1) * D_ + d] = v.y;
    rw_s[(p * 4 + 2) * D_ + d] = v.z;
    rw_s[(p * 4 + 3) * D_ + d] = v.w;
  }
  __syncthreads();
  const int wid = tid >> 6, lane = tid & 63;
  for (int ti = 0; ti < 16; ++ti) {
    const int t = blockIdx.x * 64 + wid * 16 + ti;
    const float* xr = x + (long)t * D_;
    float acc[E_] = {0.f, 0.f, 0.f, 0.f, 0.f, 0.f, 0.f, 0.f};
    for (int j = 0; j < 16; ++j) {
      const int d = lane + 64 * j;
      const float xv = xr[d];
#pragma unroll
      for (int e = 0; e < E_; ++e) acc[e] += xv * rw_s[e * D_ + d];
    }
#pragma unroll
    for (int off = 32; off >= 1; off >>= 1) {
#pragma unroll
      for (int e = 0; e < E_; ++e) acc[e] += __shfl_xor(acc[e], off, 64);
    }
    if (lane == 0) {
      int i0 = 0; float l0 = acc[0];
#pragma unroll
      for (int e = 1; e < E_; ++e) if (acc[e] > l0) { l0 = acc[e]; i0 = e; }
      int i1 = -1; float l1 = -3.4e38f;
#pragma unroll
      for (int e = 0; e < E_; ++e) if (e != i0 && acc[e] > l1) { l1 = acc[e]; i1 = e; }
      // renormalized top-2 weights: softmax denom cancels
      const float r = __expf(l1 - l0);
      const float inv = 1.f / (1.f + r);
      tok2[2 * t] = i0; tok2[2 * t + 1] = i1;
      wgt2[2 * t] = inv; wgt2[2 * t + 1] = r * inv;
      atomicAdd(&c_s[i0], 1); atomicAdd(&c_s[i1], 1);
    }
  }
  __syncthreads();
  if (tid < E_) atomicAdd(&counts[tid], c_s[tid]);
}

// ---------------- scan: 128-aligned offsets, tile->expert table ------------
__global__ void scan_kernel(const int* __restrict__ counts, int* __restrict__ offs,
                            int* __restrict__ tile_expert, int* __restrict__ rowtok) {
  __shared__ int so[10];
  const int tid = threadIdx.x;
  if (tid == 0) {
    int o = 0;
    for (int e = 0; e < E_; ++e) { so[e] = o; o += ((counts[e] + 127) >> 7) << 7; }
    so[8] = o;          // shared-expert row base
    o += T_;
    so[9] = o;          // actual total rows (<= MAXROWS)
    for (int i = 0; i < 10; ++i) offs[i] = so[i];
  }
  __syncthreads();
  for (int i = tid; i < NTILES; i += 256) {
    const int row = i << 7;
    int e = 8;
    if (row < so[8]) {
      e = 7;
      for (int k = 0; k < 7; ++k) if (row < so[k + 1]) { e = k; break; }
    }
    tile_expert[i] = e;
  }
  // default token 0 everywhere; assign_kernel overwrites the live entries
  for (int r = tid; r < MAXROWS; r += 256) rowtok[r] = 0;
}

// ---------------- assign: scatter tokens into per-expert row ranges --------
__global__ __launch_bounds__(256) void assign_kernel(
    const int* __restrict__ tok2, const int* __restrict__ offs,
    int* __restrict__ cursors, int* __restrict__ rowtok, int* __restrict__ pos2) {
  __shared__ int lcnt[E_], lbase[E_];
  const int tid = threadIdx.x;
  if (tid < E_) lcnt[tid] = 0;
  __syncthreads();
  const int t = blockIdx.x * 256 + tid;
  const int e0 = tok2[2 * t], e1 = tok2[2 * t + 1];
  const int s0 = atomicAdd(&lcnt[e0], 1);
  const int s1 = atomicAdd(&lcnt[e1], 1);
  __syncthreads();
  if (tid < E_) lbase[tid] = offs[tid] + atomicAdd(&cursors[tid], lcnt[tid]);
  __syncthreads();
  const int p0 = lbase[e0] + s0, p1 = lbase[e1] + s1;
  rowtok[p0] = t; rowtok[p1] = t;
  pos2[2 * t] = p0; pos2[2 * t + 1] = p1;
  rowtok[offs[8] + t] = t;   // shared expert: identity
}

// ---------------- x fp32 -> bf16 -------------------------------------------
__global__ __launch_bounds__(256) void cvt_x_kernel(const float* __restrict__ x,
                                                    u16* __restrict__ xb) {
  const long i = ((long)blockIdx.x * 256 + threadIdx.x) * 4;
  const float4 v = *(const float4*)(x + i);
  ushort4 o;
  o.x = (u16)f2bf_bits(v.x); o.y = (u16)f2bf_bits(v.y);
  o.z = (u16)f2bf_bits(v.z); o.w = (u16)f2bf_bits(v.w);
  *(ushort4*)(xb + i) = o;
}

// ---------------- weight transpose + fp32->bf16 ([R,C] -> [C,R]) -----------
// blockIdx.z in [0,9): z<8 -> routed expert z, z==8 -> shared weight
__global__ __launch_bounds__(256) void transpose_cvt_kernel(
    const float* __restrict__ src8, const float* __restrict__ srcShared,
    u16* __restrict__ dst, int R, int C) {
  __shared__ float tile[64][65];
  const long stride = (long)R * C;
  const float* src = (blockIdx.z < 8) ? src8 + (long)blockIdx.z * stride : srcShared;
  u16* d = dst + (long)blockIdx.z * stride;
  const int tid = threadIdx.x;
  const int r0 = blockIdx.y * 64, c0 = blockIdx.x * 64;
  const int lr = tid >> 4, lc4 = tid & 15;
#pragma unroll
  for (int p = 0; p < 4; ++p) {
    const float4 v = *(const float4*)(src + (long)(r0 + lr + 16 * p) * C + c0 + lc4 * 4);
    tile[lr + 16 * p][lc4 * 4 + 0] = v.x;
    tile[lr + 16 * p][lc4 * 4 + 1] = v.y;
    tile[lr + 16 * p][lc4 * 4 + 2] = v.z;
    tile[lr + 16 * p][lc4 * 4 + 3] = v.w;
  }
  __syncthreads();
#pragma unroll
  for (int p = 0; p < 4; ++p) {
    const int rr = lr + 16 * p;          // index along C (dst row)
    ushort4 o;
    o.x = (u16)f2bf_bits(tile[lc4 * 4 + 0][rr]);
    o.y = (u16)f2bf_bits(tile[lc4 * 4 + 1][rr]);
    o.z = (u16)f2bf_bits(tile[lc4 * 4 + 2][rr]);
    o.w = (u16)f2bf_bits(tile[lc4 * 4 + 3][rr]);
    *(ushort4*)(d + (long)(c0 + rr) * R + r0 + lc4 * 4) = o;
  }
}

// ---------------- grouped GEMM: 128x256 tile, 8-phase-style schedule --------
// G1: C[row,n] = silu( sum_k x_bf16[rowtok[row],k] * w1t[e][n,k] )  -> h bf16
// G2: C[row,n] = sum_k h[row,k] * w2t[e][n,k]                       -> eo fp32
//
// m201-template port (T3+T4+T2+T5): block 128x256, BK=32, 4 waves each owning
// a 64x128 sub-tile (FLOP per LDS-read-byte 42.7 vs 32 at 64x64). Ring-3 LDS
// (24KB/buf, 72KB total -> 2 blocks/CU). Per K-tile, 2 phases:
//   { ds_read subtile ; issue 3 global_load_lds (tile t+2) ; s_barrier ;
//     s_waitcnt lgkmcnt(0) ; setprio(1) ; 16 MFMA ; setprio(0) ; s_barrier }
// Counted vmcnt ONCE per K-tile: at the tile boundary wait vmcnt(6) -- the 6
// loads of tile t+2 stay in flight across the barrier (T4: never drain to 0
// in the main loop; drains only in the 2-tile epilogue).
// Ring safety: stage(t+2) writes buf[(t+2)%3] == buf[(t-1)%3]; tile t-1's
// ds_reads all retired before its end barrier, which every wave passed before
// issuing these stages. Residency of tile t+1 is enforced by vmcnt(6) +
// barrier before its first ds_read.
// Bank conflicts (verified 0 last round): LDS[row][c] holds global chunk
// c ^ ((row>>1)&3) (pre-swizzled SOURCE address; global_load_lds dest must be
// linear), reads use chunk quad ^ ((lr>>1)&3) -> 2-way max (free).
template <bool G1, int CHM>
__global__ __launch_bounds__(256, 2) void moe_gemm(
    const u16* __restrict__ A, const u16* __restrict__ Bt, void* __restrict__ C,
    const int* __restrict__ rowtok, const int* __restrict__ tile_expert) {
  constexpr int K = G1 ? 1024 : 4096;
  constexpr int N = G1 ? 4096 : 1024;
  constexpr int NT = N / 256;
  constexpr int NIT = K / 32;          // K-tiles of 32
  __shared__ u16 As[3 * 4096];   // 3 x (128 rows x 32 k) = 24 KB
  __shared__ u16 Bs[3 * 8192];   // 3 x (256 rows x 32 k) = 48 KB

  const int tid = threadIdx.x;
  int mt, nt;
  {
    const int bid = blockIdx.x;
    const int cb = CHM * NT;                 // blocks per full chunk
    const int chunk = bid / cb;
    const int mt0 = chunk * CHM;
    const int m = min(CHM, NTILES - mt0);    // last chunk may be short
    const int rem = bid - chunk * cb;
    mt = mt0 + rem % m;
    nt = rem / m;
  }
  const int e = tile_expert[mt];

  const int sr = tid >> 2;                       // staging row 0..63
  // pre-swizzled source chunk: LDS[row][c] <- global[row][c ^ ((row>>1)&3)]
  const int sc = (((tid & 3) ^ ((sr >> 1) & 3)) << 3);

  long aoff0, aoff1;
  if constexpr (G1) {
    aoff0 = (long)rowtok[mt * 128 + sr] * K;
    aoff1 = (long)rowtok[mt * 128 + 64 + sr] * K;
  } else {
    aoff0 = (long)(mt * 128 + sr) * K;
    aoff1 = (long)(mt * 128 + 64 + sr) * K;
  }
  const u16* pa0 = A + aoff0 + sc;
  const u16* pa1 = A + aoff1 + sc;
  const u16* pb = Bt + (long)e * N * K + (long)(nt * 256 + sr) * K + sc;

  const int lane = tid & 63;
  const int wid = tid >> 6;
  const int wm = (wid >> 1) * 64;        // 2 M-waves x 64 rows
  const int wn = (wid & 1) * 128;       // 2 N-waves x 128 cols
  const int lr = lane & 15;
  const int quad = lane >> 4;
  // swizzled read chunk (u16 elements): quad ^ ((lr>>1)&3)
  const int cA = ((quad ^ ((lr >> 1) & 3)) << 3);

  f32x4 acc[4][8] = {};

  auto stageA = [&](int b, int koff) {     // A rows 0..127 + B rows 0..63
    u16* a_d = As + b * 4096 + tid * 8;
    load_lds16(pa0 + koff, a_d);
    load_lds16(pa1 + koff, a_d + 2048);
    load_lds16(pb + koff, Bs + b * 8192 + tid * 8);
  };
  auto stageB = [&](int b, int koff) {     // B rows 64..255
    u16* b_d = Bs + b * 8192 + tid * 8;
    load_lds16(pb + (long)64 * K + koff, b_d + 2048);
    load_lds16(pb + (long)128 * K + koff, b_d + 4096);
    load_lds16(pb + (long)192 * K + koff, b_d + 6144);
  };

  // prologue: 2 K-tiles prefetched. Fence keeps tile0's 6 loads oldest.
  stageA(0, 0); stageB(0, 0);
  asm volatile("" ::: "memory");
  stageA(1, 32); stageB(1, 32);
  asm volatile("s_waitcnt vmcnt(6)\n\ts_barrier" ::: "memory");  // tile0 resident

  int cur = 0;
#pragma unroll 1
  for (int t = 0; t < NIT; ++t) {
    const int kst = (t + 2) * 32;
    const bool st = (t + 2 < NIT);
    const int nb = (cur == 0) ? 2 : cur - 1;   // (t+2)%3
    const u16* a_s = As + cur * 4096;
    const u16* b_s = Bs + cur * 8192;
    bf16x8 af[4], bv[4];

    // ---- phase A: quadrant j=0..3 (A frags read once, reused in phase B) --
#pragma unroll
    for (int i = 0; i < 4; ++i)
      af[i] = *(const bf16x8*)(a_s + (wm + i * 16 + lr) * 32 + cA);
#pragma unroll
    for (int j = 0; j < 4; ++j)
      bv[j] = *(const bf16x8*)(b_s + (wn + j * 16 + lr) * 32 + cA);
    if (st) stageA(nb, kst);
    asm volatile("s_barrier" ::: "memory");
    asm volatile("s_waitcnt lgkmcnt(0)" ::: "memory");
    __builtin_amdgcn_s_setprio(1);
#pragma unroll
    for (int i = 0; i < 4; ++i)
#pragma unroll
      for (int j = 0; j < 4; ++j)
        acc[i][j] = __builtin_amdgcn_mfma_f32_16x16x32_bf16(af[i], bv[j], acc[i][j], 0, 0, 0);
    __builtin_amdgcn_s_setprio(0);
    asm volatile("s_barrier" ::: "memory");

    // ---- phase B: quadrant j=4..7 ----------------------------------------
#pragma unroll
    for (int j = 0; j < 4; ++j)
      bv[j] = *(const bf16x8*)(b_s + (wn + (j + 4) * 16 + lr) * 32 + cA);
    if (st) stageB(nb, kst);
    asm volatile("s_barrier" ::: "memory");
    asm volatile("s_waitcnt lgkmcnt(0)" ::: "memory");
    __builtin_amdgcn_s_setprio(1);
#pragma unroll
    for (int i = 0; i < 4; ++i)
#pragma unroll
      for (int j = 0; j < 4; ++j)
        acc[i][j + 4] = __builtin_amdgcn_mfma_f32_16x16x32_bf16(af[i], bv[j], acc[i][j + 4], 0, 0, 0);
    __builtin_amdgcn_s_setprio(0);
    // ---- K-tile boundary: ensure tile t+1 resident; keep t+2 in flight ----
    if (t < NIT - 1) {
      if (st) asm volatile("s_waitcnt vmcnt(6)\n\ts_barrier" ::: "memory");
      else    asm volatile("s_waitcnt vmcnt(0)\n\ts_barrier" ::: "memory");
    }
    cur = (cur == 2) ? 0 : cur + 1;
  }

  const int rbase = mt * 128 + wm + quad * 4;
  if constexpr (G1) {
    u16* Hout = (u16*)C;
#pragma unroll
    for (int i = 0; i < 4; ++i) {
#pragma unroll
      for (int j = 0; j < 8; ++j) {
#pragma unroll
        for (int r = 0; r < 4; ++r) {
          float v = acc[i][j][r];
          v = v / (1.f + __expf(-v));            // silu
          unsigned int u = f2bf_bits(v);
          unsigned int other = (unsigned int)__shfl_xor((int)u, 1, 64);
          if (!(lane & 1)) {                      // pack col pairs -> dword store
            const unsigned int w = (u & 0xffffu) | (other << 16);
            const long row = rbase + i * 16 + r;
            const int col = nt * 256 + wn + j * 16 + lr;
            *(unsigned int*)(Hout + row * N + col) = w;
          }
        }
      }
    }
  } else {
    float* O = (float*)C;
#pragma unroll
    for (int i = 0; i < 4; ++i)
#pragma unroll
      for (int j = 0; j < 8; ++j)
#pragma unroll
        for (int r = 0; r < 4; ++r) {
          const long row = rbase + i * 16 + r;
          const int col = nt * 256 + wn + j * 16 + lr;
          O[row * N + col] = acc[i][j][r];
        }
  }
}

// ---------------- combine: out = w0*eo[p0] + w1*eo[p1] + eo[shared] ---------
__global__ __launch_bounds__(256) void combine_kernel(
    const float* __restrict__ eo, const int* __restrict__ pos2,
    const float* __restrict__ wgt2, const int* __restrict__ offs,
    float* __restrict__ out) {
  const int t = blockIdx.x, tid = threadIdx.x;
  const int p0 = pos2[2 * t], p1 = pos2[2 * t + 1];
  const float w0 = wgt2[2 * t], w1 = wgt2[2 * t + 1];
  const int ps = offs[8] + t;
  const long c = (long)tid * 4;
  const float4 a = *(const float4*)(eo + (long)p0 * D_ + c);
  const float4 b = *(const float4*)(eo + (long)p1 * D_ + c);
  const float4 s = *(const float4*)(eo + (long)ps * D_ + c);
  float4 o;
  o.x = w0 * a.x + w1 * b.x + s.x;
  o.y = w0 * a.y + w1 * b.y + s.y;
  o.z = w0 * a.z + w1 * b.z + s.z;
  o.w = w0 * a.w + w1 * b.w + s.w;
  *(float4*)(out + (long)t * D_ + c) = o;
}

// ---------------------------------------------------------------------------
extern "C" void kernel_launch(void* const* d_in, const int* in_sizes, int n_in,
                              void* d_out, int out_size, void* d_ws, size_t ws_size,
                              hipStream_t stream) {
  const float* x   = (const float*)d_in[0];   // [T, D]
  const float* rw  = (const float*)d_in[1];   // [D, E]
  const float* w1  = (const float*)d_in[2];   // [E, D, H]
  const float* w2  = (const float*)d_in[3];   // [E, H, D]
  const float* sw1 = (const float*)d_in[4];   // [D, H]
  const float* sw2 = (const float*)d_in[5];   // [H, D]
  float* out = (float*)d_out;

  char* ws = (char*)d_ws;
  int*   counts      = (int*)(ws + 0);
  int*   cursors     = (int*)(ws + 64);
  int*   offs        = (int*)(ws + 128);
  int*   tile_expert = (int*)(ws + 192);
  int*   tok2        = (int*)(ws + 4096);
  float* wgt2        = (float*)(ws + 4096 + 65536);
  int*   pos2        = (int*)(ws + 4096 + 131072);
  int*   rowtok      = (int*)(ws + 4096 + 196608);

  size_t off = 1u << 20;
  u16* xb  = (u16*)(ws + off); off += (size_t)T_ * D_ * 2;            // 16.8 MB
  u16* w1t = (u16*)(ws + off); off += (size_t)9 * H_ * D_ * 2;        // 75.5 MB
  u16* w2t = (u16*)(ws + off); off += (size_t)9 * D_ * H_ * 2;        // 75.5 MB
  u16* h   = (u16*)(ws + off); off += (size_t)MAXROWS * H_ * 2;       // 209.7 MB
  float* eo = (float*)(ws + off); off += (size_t)MAXROWS * D_ * 4;    // 104.9 MB

  hipMemsetAsync(ws, 0, 256, stream);   // counts + cursors
  router_kernel<<<128, 256, 0, stream>>>(x, rw, counts, tok2, wgt2);
  scan_kernel<<<1, 256, 0, stream>>>(counts, offs, tile_expert, rowtok);
  assign_kernel<<<32, 256, 0, stream>>>(tok2, offs, cursors, rowtok, pos2);
  cvt_x_kernel<<<T_ * D_ / 1024, 256, 0, stream>>>(x, xb);
  transpose_cvt_kernel<<<dim3(H_ / 64, D_ / 64, 9), 256, 0, stream>>>(w1, sw1, w1t, D_, H_);
  transpose_cvt_kernel<<<dim3(D_ / 64, H_ / 64, 9), 256, 0, stream>>>(w2, sw2, w2t, H_, D_);
  // G1: 200 mt x 16 nt; chunk = 32 mt x 16 nt = 512 blocks (one 2/CU fill)
  moe_gemm<true, 32><<<NTILES * (H_ / 256), 256, 0, stream>>>(xb, w1t, h, rowtok, tile_expert);
  // G2: 200 mt x 4 nt; chunk = 128 mt x 4 nt = 512 blocks
  moe_gemm<false, 128><<<NTILES * (D_ / 256), 256, 0, stream>>>(h, w2t, eo, rowtok, tile_expert);
  combine_kernel<<<T_, 256, 0, stream>>>(eo, pos2, wgt2, offs, out);
}